// Round 9
// baseline (2262.776 us; speedup 1.0000x reference)
//
#include <hip/hip_runtime.h>

#define TSTEPS 32
#define BSZ    512
#define DIN    1024
#define HID    2048
#define NCLS   10
#define BETA   0.95f
#define VTH    1.0f
#define SPKB   ((size_t)BSZ * (HID / 8))   // 131072 B: one parity buffer of packed spikes

typedef __attribute__((ext_vector_type(4))) float          f4;
typedef __attribute__((ext_vector_type(4))) float          f32x4;
typedef __attribute__((ext_vector_type(8))) __bf16         bf16x8;
typedef __attribute__((ext_vector_type(8))) unsigned short us8;
typedef __attribute__((ext_vector_type(4))) unsigned short us4;
typedef __attribute__((ext_vector_type(2))) unsigned int   u32x2;

__device__ inline unsigned short f2bf(float f) {
    unsigned u = __float_as_uint(f);
    u += 0x7FFF + ((u >> 16) & 1);          // RNE
    return (unsigned short)(u >> 16);
}
__device__ inline float bf2f(unsigned short h) {
    return __uint_as_float(((unsigned)h) << 16);
}

// split e (8 floats in two f4) into 3 exact bf16 planes
__device__ __forceinline__ void split_f4pair(f4 v0, f4 v1, us8& o0, us8& o1, us8& o2) {
#pragma unroll
    for (int jj = 0; jj < 4; jj++) {
        float v = v0[jj];
        unsigned short h1 = f2bf(v); float r = v - bf2f(h1);
        unsigned short h2 = f2bf(r); float r2 = r - bf2f(h2);
        o0[jj] = h1; o1[jj] = h2; o2[jj] = f2bf(r2);
        v = v1[jj];
        h1 = f2bf(v); r = v - bf2f(h1);
        h2 = f2bf(r); r2 = r - bf2f(h2);
        o0[jj + 4] = h1; o1[jj + 4] = h2; o2[jj + 4] = f2bf(r2);
    }
}

// ---------------------------------------------------------------------------
__global__ __launch_bounds__(256)
void split3(const float* __restrict__ w, const float* __restrict__ m,
            unsigned short* __restrict__ h1, unsigned short* __restrict__ h2,
            unsigned short* __restrict__ h3, int n4)
{
    int i      = blockIdx.x * blockDim.x + threadIdx.x;
    int stride = gridDim.x * blockDim.x;
    for (; i < n4; i += stride) {
        f4 wv = ((const f4*)w)[i];
        f4 mv = ((const f4*)m)[i];
        us4 a, b, c;
#pragma unroll
        for (int j = 0; j < 4; j++) {
            float e  = wv[j] * mv[j];
            unsigned short x1 = f2bf(e);
            float r  = e - bf2f(x1);
            unsigned short x2 = f2bf(r);
            float r2 = r - bf2f(x2);
            a[j] = x1; b[j] = x2; c[j] = f2bf(r2);
        }
        ((us4*)h1)[i] = a;
        ((us4*)h2)[i] = b;
        ((us4*)h3)[i] = c;
    }
}

// ---------------------------------------------------------------------------
// swizzled 3-plane split for [HID][HID] weights: fragment-major output.
// frag(n_tile,k_tile): lane l holds w[n_tile*16+(l&15)][k_tile*32+(l>>4)*8 ..+8]
// ---------------------------------------------------------------------------
__global__ __launch_bounds__(256)
void split3q(const float* __restrict__ w, const float* __restrict__ m,
             unsigned short* __restrict__ q)
{
    const int NK = HID * HID;
    int gid = blockIdx.x * 256 + threadIdx.x;          // 524288 threads = NK/8
    const int lane = gid & 63;
    const int t    = gid >> 6;
    const int kt   = t & (HID / 32 - 1);               // & 63
    const int nt   = t >> 6;
    const int n = nt * 16 + (lane & 15);
    const int k = kt * 32 + (lane >> 4) * 8;
    const size_t src = (size_t)n * HID + k;
    f4 w0 = *(const f4*)(w + src),     w1v = *(const f4*)(w + src + 4);
    f4 m0 = *(const f4*)(m + src),     m1v = *(const f4*)(m + src + 4);
    us8 q0, q1, q2;
    split_f4pair(w0 * m0, w1v * m1v, q0, q1, q2);
    ((us8*)q)[gid]            = q0;
    ((us8*)(q + NK))[gid]     = q1;
    ((us8*)(q + 2 * NK))[gid] = q2;
}

__global__ __launch_bounds__(256)
void zerof(float* __restrict__ p, int n4)
{
    int i      = blockIdx.x * blockDim.x + threadIdx.x;
    int stride = gridDim.x * blockDim.x;
    f4 z = {0.f, 0.f, 0.f, 0.f};
    for (; i < n4; i += stride) ((f4*)p)[i] = z;
}

// split x_t into 3 bf16 planes (LINEAR layout; for L1 role_l1s)
__device__ __forceinline__ void xsplit_dev(const float* __restrict__ xt,
                                           unsigned short* __restrict__ dst,
                                           int bid, int nblk, int tid)
{
    const int n4 = BSZ * DIN / 4;              // 131072
    const int PS = BSZ * DIN;
    int i      = bid * 256 + tid;
    int stride = nblk * 256;
    for (; i < n4; i += stride) {
        f4 v = ((const f4*)xt)[i];
        us4 a, b, c;
#pragma unroll
        for (int j = 0; j < 4; j++) {
            float e = v[j];
            unsigned short x1 = f2bf(e);
            float r  = e - bf2f(x1);
            unsigned short x2 = f2bf(r);
            float r2 = r - bf2f(x2);
            a[j] = x1; b[j] = x2; c[j] = f2bf(r2);
        }
        ((us4*)(dst))[i]          = a;
        ((us4*)(dst + PS))[i]     = b;
        ((us4*)(dst + 2 * PS))[i] = c;
    }
}

__global__ __launch_bounds__(256)
void xsplit_k(const float* __restrict__ xt, unsigned short* __restrict__ dst)
{
    xsplit_dev(xt, dst, blockIdx.x, gridDim.x, threadIdx.x);
}

// ---------------------------------------------------------------------------
// LIF epilogue (2x2 wave tile): mem RMW + ballot-packed spike bits
// C/D mapping (verified m89/m91): col = lane&15, row = (lane>>4)*4 + reg
// ---------------------------------------------------------------------------
__device__ __forceinline__ void lif_epi(const f32x4 acc[2][2], const float* __restrict__ bias,
                                        float* __restrict__ memOut, unsigned char* __restrict__ sbits,
                                        int bm, int bn, int wm, int wn, int lane)
{
    const int fr = lane & 15;
#pragma unroll
    for (int fm = 0; fm < 2; fm++)
#pragma unroll
        for (int fn = 0; fn < 2; fn++) {
            const int n  = bn * 64 + wn * 32 + fn * 16 + fr;
            const float bv = bias[n];
            const int rbase = bm * 64 + wm * 32 + fm * 16 + (lane >> 4) * 4;
#pragma unroll
            for (int r = 0; r < 4; r++) {
                const int row = rbase + r;
                float* mp = memOut + (size_t)row * HID + n;
                float mo  = *mp;
                float m2  = BETA * mo + (acc[fm][fn][r] + bv) - ((mo > VTH) ? VTH : 0.f);
                *mp = m2;
                unsigned long long bal = __ballot(m2 > VTH);
                if (fr == 0) {
                    unsigned short bits = (unsigned short)(bal >> ((lane >> 4) * 16));
                    *(unsigned short*)(sbits + (size_t)row * (HID / 8) + bn * 8 + wn * 4 + fn * 2) = bits;
                }
            }
        }
}

// LIF epilogue for 128x16 wave tile (acc[fm], fm=0..7; wave wv owns 16 cols;
// block = 128 rows x 64 cols). Extension of verified lif_epi4b.
__device__ __forceinline__ void lif_epi8b(const f32x4 (&acc)[8], const float* __restrict__ bias,
                                          float* __restrict__ memOut,
                                          unsigned char* __restrict__ sbitsOut,
                                          int bm, int bn, int wv, int lane)
{
    const int fr = lane & 15;
    const int n  = bn * 64 + wv * 16 + fr;
    const float bv = bias[n];
#pragma unroll
    for (int fm = 0; fm < 8; fm++) {
        const int rbase = bm * 128 + fm * 16 + (lane >> 4) * 4;
#pragma unroll
        for (int r = 0; r < 4; r++) {
            const int row = rbase + r;
            float* mp = memOut + (size_t)row * HID + n;
            float mo  = *mp;
            float m2  = BETA * mo + (acc[fm][r] + bv) - ((mo > VTH) ? VTH : 0.f);
            *mp = m2;
            unsigned long long bal = __ballot(m2 > VTH);
            if (fr == 0) {
                unsigned short bits = (unsigned short)(bal >> ((lane >> 4) * 16));
                *(unsigned short*)(sbitsOut + (size_t)row * (HID / 8) + bn * 8 + wv * 2) = bits;
            }
        }
    }
}

// ---------------------------------------------------------------------------
// Output layer: A = packed spike bits (uint per lane = 32 cols), wave per row.
// ---------------------------------------------------------------------------
__device__ __forceinline__ void role_out_b(const unsigned char* __restrict__ sbits,
    const float* __restrict__ wo, const float* __restrict__ bo,
    float* __restrict__ memo, float* __restrict__ ssum, int b, int lane)
{
    const unsigned int bits = *(const unsigned int*)(sbits + (size_t)b * (HID / 8) + lane * 4);
    float acc[NCLS];
#pragma unroll
    for (int c = 0; c < NCLS; c++) {
        const f4* wrow = (const f4*)(wo + (size_t)c * HID + lane * 32);
        float s = 0.f;
#pragma unroll
        for (int q = 0; q < 8; q++) {
            f4 w = wrow[q];
#pragma unroll
            for (int i = 0; i < 4; i++)
                if ((bits >> (q * 4 + i)) & 1u) s += w[i];
        }
        acc[c] = s;
    }
#pragma unroll
    for (int c = 0; c < NCLS; c++)
#pragma unroll
        for (int m = 1; m < 64; m <<= 1) acc[c] += __shfl_xor(acc[c], m, 64);

    if (lane == 0) {
#pragma unroll
        for (int c = 0; c < NCLS; c++) {
            float mo  = memo[b * NCLS + c];
            float rst = (mo > VTH) ? VTH : 0.f;
            float m2  = BETA * mo + acc[c] + bo[c] - rst;
            memo[b * NCLS + c] = m2;
            if (m2 > VTH) ssum[b * NCLS + c] += 1.f;
        }
    }
}

// ===========================================================================
// V9 L2/L3: M=128 row-block (wave tile 128x16, acc[8], 24 MFMA/step).
// Halves B-plane read demand vs V4 (each 768KB panel read by 4 blocks not 8)
// -> L3 demand 402MB -> 201MB/dispatch. XCD-affine mapping puts the 4 blocks
// sharing a panel on one XCD so re-reads hit its private L2 (3MB/4MB).
// Inner loop, A-bitmap path, LUT, B-prefetch depth-2, per-acc MFMA order
// (b0,b1,b2; k ascending) are verbatim V4 -> bit-identical accumulation.
// ===========================================================================
__device__ __forceinline__ void role_l23m(unsigned char* smem,
    const unsigned char* __restrict__ sbitsIn,
    const unsigned short* __restrict__ Bq,      // 3 swizzled planes, stride HID*HID
    const float* __restrict__ bias, float* __restrict__ memOut,
    unsigned char* __restrict__ sbitsOut, int g, int tid)
{
    u32x2* lut = (u32x2*)smem;                  // 16 x 8 B
    if (tid < 16) {
        u32x2 e;
        e.x = ((tid & 1) ? 0x3F80u : 0u) | ((tid & 2) ? 0x3F800000u : 0u);
        e.y = ((tid & 4) ? 0x3F80u : 0u) | ((tid & 8) ? 0x3F800000u : 0u);
        lut[tid] = e;
    }
    __syncthreads();

    // XCD-affine decode (g in 0..127): blocks sharing a panel bn share bid%8.
    const int xcd = g & 7, pg = (g >> 3) & 3, bm = g >> 5;   // bm 0..3
    const int bn  = xcd + pg * 8;                            // 0..31

    const int lane = tid & 63, wv = tid >> 6;
    const int fr = lane & 15, fk = (lane >> 4) * 8;

    const size_t PSQ = (size_t)HID * HID / 8;
    const us8* bP0 = (const us8*)Bq + (size_t)(bn * 4 + wv) * (HID / 32) * 64 + lane;
    const us8* bP1 = bP0 + PSQ;
    const us8* bP2 = bP1 + PSQ;

    const unsigned char* aR = sbitsIn + (size_t)(bm * 128 + fr) * (HID / 8);

    f32x4 acc[8] = {};
    us8 bb[2][3];
    us4 awq[2][8];

#define LDB4(SET, S) do { const int sc_ = (S) < 64 ? (S) : 63;                 \
        bb[SET][0] = bP0[sc_ * 64];                                            \
        bb[SET][1] = bP1[sc_ * 64];                                            \
        bb[SET][2] = bP2[sc_ * 64]; } while (0)

#define LDA8(SET, G) do { const int gc_ = (G) < 16 ? (G) : 15;                 \
        awq[SET][0] = *(const us4*)(aR + 0 * 16 * (HID / 8) + gc_ * 16);       \
        awq[SET][1] = *(const us4*)(aR + 1 * 16 * (HID / 8) + gc_ * 16);       \
        awq[SET][2] = *(const us4*)(aR + 2 * 16 * (HID / 8) + gc_ * 16);       \
        awq[SET][3] = *(const us4*)(aR + 3 * 16 * (HID / 8) + gc_ * 16);       \
        awq[SET][4] = *(const us4*)(aR + 4 * 16 * (HID / 8) + gc_ * 16);       \
        awq[SET][5] = *(const us4*)(aR + 5 * 16 * (HID / 8) + gc_ * 16);       \
        awq[SET][6] = *(const us4*)(aR + 6 * 16 * (HID / 8) + gc_ * 16);       \
        awq[SET][7] = *(const us4*)(aR + 7 * 16 * (HID / 8) + gc_ * 16); } while (0)

#define EXPAND(AF, W) do { unsigned by_ = ((W) >> fk) & 0xFFu;                 \
        u32x2 lo_ = lut[by_ & 15u];                                            \
        u32x2 hi_ = lut[by_ >> 4];                                             \
        ((u32x2*)&(AF))[0] = lo_;                                              \
        ((u32x2*)&(AF))[1] = hi_; } while (0)

#define MMQ(AX, IDX) do {                                                      \
        bf16x8 fa_ = *(const bf16x8*)&AX;                                      \
        acc[IDX] = __builtin_amdgcn_mfma_f32_16x16x32_bf16(fa_, b0_, acc[IDX], 0, 0, 0); \
        acc[IDX] = __builtin_amdgcn_mfma_f32_16x16x32_bf16(fa_, b1_, acc[IDX], 0, 0, 0); \
        acc[IDX] = __builtin_amdgcn_mfma_f32_16x16x32_bf16(fa_, b2_, acc[IDX], 0, 0, 0); \
    } while (0)

#define STEP(BSET, ASET, COMP) do {                                            \
        bf16x8 b0_ = *(const bf16x8*)&bb[BSET][0];                             \
        bf16x8 b1_ = *(const bf16x8*)&bb[BSET][1];                             \
        bf16x8 b2_ = *(const bf16x8*)&bb[BSET][2];                             \
        us8 a0_, a1_, a2_, a3_;                                                \
        EXPAND(a0_, awq[ASET][0][COMP]);                                       \
        EXPAND(a1_, awq[ASET][1][COMP]);                                       \
        EXPAND(a2_, awq[ASET][2][COMP]);                                       \
        EXPAND(a3_, awq[ASET][3][COMP]);                                       \
        MMQ(a0_, 0); MMQ(a1_, 1); MMQ(a2_, 2); MMQ(a3_, 3);                    \
        us8 a4_, a5_, a6_, a7_;                                                \
        EXPAND(a4_, awq[ASET][4][COMP]);                                       \
        EXPAND(a5_, awq[ASET][5][COMP]);                                       \
        EXPAND(a6_, awq[ASET][6][COMP]);                                       \
        EXPAND(a7_, awq[ASET][7][COMP]);                                       \
        MMQ(a4_, 4); MMQ(a5_, 5); MMQ(a6_, 6); MMQ(a7_, 7);                    \
    } while (0)

    LDB4(0, 0); LDB4(1, 1);
    LDA8(0, 0); LDA8(1, 1);

    for (int gg = 0; gg < 16; gg += 2) {
        const int s0 = gg * 4;
        STEP(0, 0, 0); LDB4(0, s0 + 2);
        STEP(1, 0, 1); LDB4(1, s0 + 3);
        STEP(0, 0, 2); LDB4(0, s0 + 4);
        STEP(1, 0, 3); LDB4(1, s0 + 5);
        LDA8(0, gg + 2);
        STEP(0, 1, 0); LDB4(0, s0 + 6);
        STEP(1, 1, 1); LDB4(1, s0 + 7);
        STEP(0, 1, 2); LDB4(0, s0 + 8);
        STEP(1, 1, 3); LDB4(1, s0 + 9);
        LDA8(1, gg + 3);
    }

#undef LDB4
#undef LDA8
#undef EXPAND
#undef MMQ
#undef STEP

    lif_epi8b(acc, bias, memOut, sbitsOut, bm, bn, wv, lane);
}

// ===========================================================================
// V4 Layer 1 (verified): LDS single-buffered As[3]+Bs[3] (30720 B)
// ===========================================================================
__device__ __forceinline__ void role_l1s(unsigned char* smem,
    const unsigned short* __restrict__ Ap,
    const unsigned short* __restrict__ Wp,
    const float* __restrict__ bias, float* __restrict__ memOut,
    unsigned char* __restrict__ sbitsOut, int rb, int tid)
{
    auto As = reinterpret_cast<unsigned short(*)[64 * 40]>(smem);              // [3]
    auto Bs = reinterpret_cast<unsigned short(*)[64 * 40]>(smem + 15360);      // [3]
    const size_t APS = (size_t)BSZ * DIN;
    const size_t BPS = (size_t)HID * DIN;

    const int bn = rb & 31, bm = rb >> 5;
    const int srow = tid >> 2, skq = tid & 3;
    const int lane = tid & 63, wv = tid >> 6;
    const int wm = wv >> 1, wn = wv & 1;
    const int fr = lane & 15, fk = (lane >> 4) * 8;
    const size_t aRow = (size_t)(bm * 64 + srow) * DIN;
    const size_t bRow = (size_t)(bn * 64 + srow) * DIN;
    const int sdst = srow * 40 + skq * 8;

    f32x4 acc[2][2] = {};
    us8 aa0, aa1, aa2, bb0, bb1, bb2;

    auto ldnext = [&](int k0) {
        aa0 = *(const us8*)(Ap + aRow + k0 + skq * 8);
        aa1 = *(const us8*)(Ap + APS + aRow + k0 + skq * 8);
        aa2 = *(const us8*)(Ap + 2 * APS + aRow + k0 + skq * 8);
        bb0 = *(const us8*)(Wp + bRow + k0 + skq * 8);
        bb1 = *(const us8*)(Wp + BPS + bRow + k0 + skq * 8);
        bb2 = *(const us8*)(Wp + 2 * BPS + bRow + k0 + skq * 8);
    };
    auto stageAB = [&]() {
        *(us8*)&As[0][sdst] = aa0;
        *(us8*)&As[1][sdst] = aa1;
        *(us8*)&As[2][sdst] = aa2;
        *(us8*)&Bs[0][sdst] = bb0;
        *(us8*)&Bs[1][sdst] = bb1;
        *(us8*)&Bs[2][sdst] = bb2;
    };

    ldnext(0); stageAB();
    __syncthreads();

    const int nsteps = DIN / 32;      // 32
    for (int s = 0; s < nsteps; s++) {
        const bool more = (s + 1 < nsteps);
        if (more) ldnext((s + 1) * 32);

        bf16x8 af[3][2], bf[3][2];
#pragma unroll
        for (int p = 0; p < 3; p++)
#pragma unroll
            for (int f = 0; f < 2; f++) {
                af[p][f] = *(const bf16x8*)&As[p][(wm * 32 + f * 16 + fr) * 40 + fk];
                bf[p][f] = *(const bf16x8*)&Bs[p][(wn * 32 + f * 16 + fr) * 40 + fk];
            }
#pragma unroll
        for (int pa = 0; pa < 3; pa++)
#pragma unroll
            for (int pb = 0; pb < 3; pb++) {
                if (pa + pb <= 2) {
#pragma unroll
                    for (int fm = 0; fm < 2; fm++)
#pragma unroll
                        for (int fn = 0; fn < 2; fn++)
                            acc[fm][fn] = __builtin_amdgcn_mfma_f32_16x16x32_bf16(
                                af[pa][fm], bf[pb][fn], acc[fm][fn], 0, 0, 0);
                }
            }

        __syncthreads();
        if (more) stageAB();
        __syncthreads();
    }

    lif_epi(acc, bias, memOut, sbitsOut, bm, bn, wm, wn, lane);
}

// ---------------------------------------------------------------------------
// V9 fused pipeline step (diagonal j), grid 768 = 3 blocks/CU:
//   L1(t=j):256 | L2(t=j-1):128 | L3(t=j-2):128 | XS(t=j+1)+OUT(t=j-3):256
// bid, bid+256, bid+512 co-locate on one CU -> each CU gets {L1, L23, XS/OUT}.
// ---------------------------------------------------------------------------
__global__ __launch_bounds__(256, 3)
void snn_step9(const float* __restrict__ x,
               unsigned short* __restrict__ xp,
               const unsigned short* __restrict__ w1p, const float* __restrict__ b1,
               const unsigned short* __restrict__ w2q, const float* __restrict__ b2,
               const unsigned short* __restrict__ w3q, const float* __restrict__ b3,
               const float* __restrict__ wo, const float* __restrict__ bo,
               float* __restrict__ mem1, float* __restrict__ mem2, float* __restrict__ mem3,
               float* __restrict__ memo,
               unsigned char* __restrict__ spk1, unsigned char* __restrict__ spk2,
               unsigned char* __restrict__ spk3,
               float* __restrict__ ssum, int j)
{
    __shared__ __align__(16) unsigned char smem[30720];
    const int bid = blockIdx.x, tid = threadIdx.x;
    const size_t XSLOT = (size_t)3 * BSZ * DIN;

    if (bid < 256) {
        const int t = j;
        if (t <= TSTEPS - 1)
            role_l1s(smem, xp + (size_t)(t & 1) * XSLOT, w1p, b1, mem1,
                     spk1 + (size_t)(t & 1) * SPKB, bid, tid);
    } else if (bid < 384) {
        const int t = j - 1;
        if (t >= 0 && t <= TSTEPS - 1)
            role_l23m(smem, spk1 + (size_t)(t & 1) * SPKB, w2q, b2, mem2,
                      spk2 + (size_t)(t & 1) * SPKB, bid - 256, tid);
    } else if (bid < 512) {
        const int t = j - 2;
        if (t >= 0 && t <= TSTEPS - 1)
            role_l23m(smem, spk2 + (size_t)(t & 1) * SPKB, w3q, b3, mem3,
                      spk3 + (size_t)(t & 1) * SPKB, bid - 384, tid);
    } else {
        const int t1 = j + 1;
        if (t1 <= TSTEPS - 1)
            xsplit_dev(x + (size_t)t1 * BSZ * DIN,
                       xp + (size_t)(t1 & 1) * XSLOT, bid - 512, 256, tid);
        const int t = j - 3;
        if (t >= 0 && t <= TSTEPS - 1) {
            const int lane = tid & 63, wvi = tid >> 6;
            if (wvi < 2)
                role_out_b(spk3 + (size_t)(t & 1) * SPKB, wo, bo, memo, ssum,
                           (bid - 512) * 2 + wvi, lane);
        }
    }
}

// ---------------------------------------------------------------------------
extern "C" void kernel_launch(void* const* d_in, const int* in_sizes, int n_in,
                              void* d_out, int out_size, void* d_ws, size_t ws_size,
                              hipStream_t stream)
{
    const float* x  = (const float*)d_in[0];
    const float* w1 = (const float*)d_in[1];
    const float* b1 = (const float*)d_in[2];
    const float* m1 = (const float*)d_in[3];
    const float* w2 = (const float*)d_in[4];
    const float* b2 = (const float*)d_in[5];
    const float* m2 = (const float*)d_in[6];
    const float* w3 = (const float*)d_in[7];
    const float* b3 = (const float*)d_in[8];
    const float* m3 = (const float*)d_in[9];
    const float* wo = (const float*)d_in[10];
    const float* bo = (const float*)d_in[11];
    float* out = (float*)d_out;

    const size_t planeB  = (size_t)HID * HID * 2;   // 8,388,608
    const size_t plane1B = (size_t)HID * DIN * 2;   // 4,194,304
    const size_t planeXB = (size_t)BSZ * DIN * 2;   // 1,048,576
    const size_t memB    = (size_t)BSZ * HID * 4;   // 4,194,304
    const size_t memoB   = (size_t)BSZ * NCLS * 4;  // 20,480
    const size_t spk2B   = 2 * SPKB;                // 262,144

    unsigned char* base = (unsigned char*)d_ws;
    const int nW1  = HID * DIN / 4;
    const size_t HD = (size_t)HID * DIN;

    const size_t needV9 = 6 * planeB + 3 * plane1B + 6 * planeXB
                        + 3 * memB + memoB + 3 * spk2B + 4096;   // 82,599,936
    if (ws_size < needV9) return;   // harness provides more (verified R4-R8)

    unsigned short* w2q = (unsigned short*)base;
    unsigned short* w3q = (unsigned short*)(base + 3 * planeB);
    unsigned short* w1p = (unsigned short*)(base + 6 * planeB);
    unsigned short* xp  = (unsigned short*)(base + 6 * planeB + 3 * plane1B);
    unsigned char* mbase = base + 6 * planeB + 3 * plane1B + 6 * planeXB;
    float* mem1 = (float*)(mbase);
    float* mem2 = (float*)(mbase + memB);
    float* mem3 = (float*)(mbase + 2 * memB);
    float* memo = (float*)(mbase + 3 * memB);
    unsigned char* spk1 = mbase + 3 * memB + memoB;
    unsigned char* spk2 = spk1 + spk2B;
    unsigned char* spk3 = spk2 + spk2B;

    split3q<<<2048, 256, 0, stream>>>(w2, m2, w2q);
    split3q<<<2048, 256, 0, stream>>>(w3, m3, w3q);
    split3<<<1024, 256, 0, stream>>>(w1, m1, w1p, w1p + HD, w1p + 2 * HD, nW1);
    xsplit_k<<<256, 256, 0, stream>>>(x, xp);   // t=0 into slot 0

    zerof<<<1024, 256, 0, stream>>>(mem1, (int)((3 * memB + memoB) / 16));
    zerof<<<8, 256, 0, stream>>>(out, (BSZ * NCLS) / 4);

    for (int j = 0; j <= TSTEPS + 2; j++) {   // 35 diagonals
        snn_step9<<<768, 256, 0, stream>>>(x, xp, w1p, b1, w2q, b2, w3q, b3,
                                           wo, bo, mem1, mem2, mem3, memo,
                                           spk1, spk2, spk3, out, j);
    }
}

// Round 10
// 1739.475 us; speedup vs baseline: 1.3008x; 1.3008x over previous
//
#include <hip/hip_runtime.h>

#define TSTEPS 32
#define BSZ    512
#define DIN    1024
#define HID    2048
#define NCLS   10
#define BETA   0.95f
#define VTH    1.0f
#define SPKB   ((size_t)BSZ * (HID / 8))   // 131072 B: one parity buffer of packed spikes

typedef __attribute__((ext_vector_type(4))) float          f4;
typedef __attribute__((ext_vector_type(4))) float          f32x4;
typedef __attribute__((ext_vector_type(8))) __bf16         bf16x8;
typedef __attribute__((ext_vector_type(8))) unsigned short us8;
typedef __attribute__((ext_vector_type(4))) unsigned short us4;
typedef __attribute__((ext_vector_type(2))) unsigned int   u32x2;

__device__ inline unsigned short f2bf(float f) {
    unsigned u = __float_as_uint(f);
    u += 0x7FFF + ((u >> 16) & 1);          // RNE
    return (unsigned short)(u >> 16);
}
__device__ inline float bf2f(unsigned short h) {
    return __uint_as_float(((unsigned)h) << 16);
}

// split e (8 floats in two f4) into 3 exact bf16 planes
__device__ __forceinline__ void split_f4pair(f4 v0, f4 v1, us8& o0, us8& o1, us8& o2) {
#pragma unroll
    for (int jj = 0; jj < 4; jj++) {
        float v = v0[jj];
        unsigned short h1 = f2bf(v); float r = v - bf2f(h1);
        unsigned short h2 = f2bf(r); float r2 = r - bf2f(h2);
        o0[jj] = h1; o1[jj] = h2; o2[jj] = f2bf(r2);
        v = v1[jj];
        h1 = f2bf(v); r = v - bf2f(h1);
        h2 = f2bf(r); r2 = r - bf2f(h2);
        o0[jj + 4] = h1; o1[jj + 4] = h2; o2[jj + 4] = f2bf(r2);
    }
}

// ---------------------------------------------------------------------------
__global__ __launch_bounds__(256)
void split3(const float* __restrict__ w, const float* __restrict__ m,
            unsigned short* __restrict__ h1, unsigned short* __restrict__ h2,
            unsigned short* __restrict__ h3, int n4)
{
    int i      = blockIdx.x * blockDim.x + threadIdx.x;
    int stride = gridDim.x * blockDim.x;
    for (; i < n4; i += stride) {
        f4 wv = ((const f4*)w)[i];
        f4 mv = ((const f4*)m)[i];
        us4 a, b, c;
#pragma unroll
        for (int j = 0; j < 4; j++) {
            float e  = wv[j] * mv[j];
            unsigned short x1 = f2bf(e);
            float r  = e - bf2f(x1);
            unsigned short x2 = f2bf(r);
            float r2 = r - bf2f(x2);
            a[j] = x1; b[j] = x2; c[j] = f2bf(r2);
        }
        ((us4*)h1)[i] = a;
        ((us4*)h2)[i] = b;
        ((us4*)h3)[i] = c;
    }
}

// ---------------------------------------------------------------------------
// swizzled 3-plane split for [HID][HID] weights: fragment-major output.
// frag(n_tile,k_tile): lane l holds w[n_tile*16+(l&15)][k_tile*32+(l>>4)*8 ..+8]
// ---------------------------------------------------------------------------
__global__ __launch_bounds__(256)
void split3q(const float* __restrict__ w, const float* __restrict__ m,
             unsigned short* __restrict__ q)
{
    const int NK = HID * HID;
    int gid = blockIdx.x * 256 + threadIdx.x;          // 524288 threads = NK/8
    const int lane = gid & 63;
    const int t    = gid >> 6;
    const int kt   = t & (HID / 32 - 1);               // & 63
    const int nt   = t >> 6;
    const int n = nt * 16 + (lane & 15);
    const int k = kt * 32 + (lane >> 4) * 8;
    const size_t src = (size_t)n * HID + k;
    f4 w0 = *(const f4*)(w + src),     w1v = *(const f4*)(w + src + 4);
    f4 m0 = *(const f4*)(m + src),     m1v = *(const f4*)(m + src + 4);
    us8 q0, q1, q2;
    split_f4pair(w0 * m0, w1v * m1v, q0, q1, q2);
    ((us8*)q)[gid]            = q0;
    ((us8*)(q + NK))[gid]     = q1;
    ((us8*)(q + 2 * NK))[gid] = q2;
}

__global__ __launch_bounds__(256)
void zerof(float* __restrict__ p, int n4)
{
    int i      = blockIdx.x * blockDim.x + threadIdx.x;
    int stride = gridDim.x * blockDim.x;
    f4 z = {0.f, 0.f, 0.f, 0.f};
    for (; i < n4; i += stride) ((f4*)p)[i] = z;
}

// split x_t into 3 bf16 planes (LINEAR layout; for L1 role_l1s)
__device__ __forceinline__ void xsplit_dev(const float* __restrict__ xt,
                                           unsigned short* __restrict__ dst,
                                           int bid, int nblk, int tid)
{
    const int n4 = BSZ * DIN / 4;              // 131072
    const int PS = BSZ * DIN;
    int i      = bid * 256 + tid;
    int stride = nblk * 256;
    for (; i < n4; i += stride) {
        f4 v = ((const f4*)xt)[i];
        us4 a, b, c;
#pragma unroll
        for (int j = 0; j < 4; j++) {
            float e = v[j];
            unsigned short x1 = f2bf(e);
            float r  = e - bf2f(x1);
            unsigned short x2 = f2bf(r);
            float r2 = r - bf2f(x2);
            a[j] = x1; b[j] = x2; c[j] = f2bf(r2);
        }
        ((us4*)(dst))[i]          = a;
        ((us4*)(dst + PS))[i]     = b;
        ((us4*)(dst + 2 * PS))[i] = c;
    }
}

__global__ __launch_bounds__(256)
void xsplit_k(const float* __restrict__ xt, unsigned short* __restrict__ dst)
{
    xsplit_dev(xt, dst, blockIdx.x, gridDim.x, threadIdx.x);
}

// ---------------------------------------------------------------------------
// LIF epilogue (2x2 wave tile): mem RMW + ballot-packed spike bits
// C/D mapping (verified m89/m91): col = lane&15, row = (lane>>4)*4 + reg
// ---------------------------------------------------------------------------
__device__ __forceinline__ void lif_epi(const f32x4 acc[2][2], const float* __restrict__ bias,
                                        float* __restrict__ memOut, unsigned char* __restrict__ sbits,
                                        int bm, int bn, int wm, int wn, int lane)
{
    const int fr = lane & 15;
#pragma unroll
    for (int fm = 0; fm < 2; fm++)
#pragma unroll
        for (int fn = 0; fn < 2; fn++) {
            const int n  = bn * 64 + wn * 32 + fn * 16 + fr;
            const float bv = bias[n];
            const int rbase = bm * 64 + wm * 32 + fm * 16 + (lane >> 4) * 4;
#pragma unroll
            for (int r = 0; r < 4; r++) {
                const int row = rbase + r;
                float* mp = memOut + (size_t)row * HID + n;
                float mo  = *mp;
                float m2  = BETA * mo + (acc[fm][fn][r] + bv) - ((mo > VTH) ? VTH : 0.f);
                *mp = m2;
                unsigned long long bal = __ballot(m2 > VTH);
                if (fr == 0) {
                    unsigned short bits = (unsigned short)(bal >> ((lane >> 4) * 16));
                    *(unsigned short*)(sbits + (size_t)row * (HID / 8) + bn * 8 + wn * 4 + fn * 2) = bits;
                }
            }
        }
}

// LIF epilogue for a 64x16 wave tile at explicit row/col bases (acc[fm], fm=0..3;
// this wave owns 16 cols at colBase). Same per-element math/ballot as verified
// lif_epi4b, only the base arithmetic is generalized.
__device__ __forceinline__ void lif_epi4c(const f32x4 (&acc)[4], const float* __restrict__ bias,
                                          float* __restrict__ memOut,
                                          unsigned char* __restrict__ sbitsOut,
                                          int rowBase, int colBase, int lane)
{
    const int fr = lane & 15;
    const int n  = colBase + fr;
    const float bv = bias[n];
#pragma unroll
    for (int fm = 0; fm < 4; fm++) {
        const int rbase = rowBase + fm * 16 + (lane >> 4) * 4;
#pragma unroll
        for (int r = 0; r < 4; r++) {
            const int row = rbase + r;
            float* mp = memOut + (size_t)row * HID + n;
            float mo  = *mp;
            float m2  = BETA * mo + (acc[fm][r] + bv) - ((mo > VTH) ? VTH : 0.f);
            *mp = m2;
            unsigned long long bal = __ballot(m2 > VTH);
            if (fr == 0) {
                unsigned short bits = (unsigned short)(bal >> ((lane >> 4) * 16));
                *(unsigned short*)(sbitsOut + (size_t)row * (HID / 8) + (colBase >> 3)) = bits;
            }
        }
    }
}

// ---------------------------------------------------------------------------
// Output layer: A = packed spike bits (uint per lane = 32 cols), wave per row.
// ---------------------------------------------------------------------------
__device__ __forceinline__ void role_out_b(const unsigned char* __restrict__ sbits,
    const float* __restrict__ wo, const float* __restrict__ bo,
    float* __restrict__ memo, float* __restrict__ ssum, int b, int lane)
{
    const unsigned int bits = *(const unsigned int*)(sbits + (size_t)b * (HID / 8) + lane * 4);
    float acc[NCLS];
#pragma unroll
    for (int c = 0; c < NCLS; c++) {
        const f4* wrow = (const f4*)(wo + (size_t)c * HID + lane * 32);
        float s = 0.f;
#pragma unroll
        for (int q = 0; q < 8; q++) {
            f4 w = wrow[q];
#pragma unroll
            for (int i = 0; i < 4; i++)
                if ((bits >> (q * 4 + i)) & 1u) s += w[i];
        }
        acc[c] = s;
    }
#pragma unroll
    for (int c = 0; c < NCLS; c++)
#pragma unroll
        for (int m = 1; m < 64; m <<= 1) acc[c] += __shfl_xor(acc[c], m, 64);

    if (lane == 0) {
#pragma unroll
        for (int c = 0; c < NCLS; c++) {
            float mo  = memo[b * NCLS + c];
            float rst = (mo > VTH) ? VTH : 0.f;
            float m2  = BETA * mo + acc[c] + bo[c] - rst;
            memo[b * NCLS + c] = m2;
            if (m2 > VTH) ssum[b * NCLS + c] += 1.f;
        }
    }
}

// ===========================================================================
// V10 L2/L3: block = M=128 x N=32, 4 waves = 2 row-groups x 2 col-groups,
// wave tile 64x16 (acc[4], verbatim V4 per-wave shape & inner loop).
// Wave pairs (0,2) and (1,3) read IDENTICAL B fragments (same 16 cols) ->
// second wave's loads hit per-CU L1 -> L2/L3-side B demand halves vs V4
// (402 -> 201 MB/dispatch). 256 blocks/layer -> grid 1024 keeps V4's
// co-residency (each CU: L1 + one L2 + one L3 + XS/OUT).
// Per-acc MFMA order (b0,b1,b2; k ascending) verbatim V4 -> bit-identical.
// ===========================================================================
__device__ __forceinline__ void role_l23p(unsigned char* smem,
    const unsigned char* __restrict__ sbitsIn,
    const unsigned short* __restrict__ Bq,      // 3 swizzled planes, stride HID*HID
    const float* __restrict__ bias, float* __restrict__ memOut,
    unsigned char* __restrict__ sbitsOut, int rb, int tid)
{
    u32x2* lut = (u32x2*)smem;                  // 16 x 8 B
    if (tid < 16) {
        u32x2 e;
        e.x = ((tid & 1) ? 0x3F80u : 0u) | ((tid & 2) ? 0x3F800000u : 0u);
        e.y = ((tid & 4) ? 0x3F80u : 0u) | ((tid & 8) ? 0x3F800000u : 0u);
        lut[tid] = e;
    }
    __syncthreads();

    const int bn = rb & 63, bm = rb >> 6;       // bn 0..63 (32-col panel), bm 0..3 (128-row)
    const int lane = tid & 63, wv = tid >> 6;
    const int rg = wv >> 1, cg = wv & 1;        // row-group, col-group
    const int fr = lane & 15, fk = (lane >> 4) * 8;

    const int nt = bn * 2 + cg;                 // 16-col fragment tile 0..127
    const us8* bP0 = (const us8*)Bq + (size_t)nt * (HID / 32) * 64 + lane;
    const us8* bP1 = bP0 + (size_t)HID * HID / 8;
    const us8* bP2 = bP1 + (size_t)HID * HID / 8;

    const int rowBase = bm * 128 + rg * 64;
    const unsigned char* aR = sbitsIn + (size_t)(rowBase + fr) * (HID / 8);

    f32x4 acc[4] = {};
    us8 bb[2][3];
    us4 awq[2][4];

#define LDB4(SET, S) do { const int sc_ = (S) < 64 ? (S) : 63;                 \
        bb[SET][0] = bP0[sc_ * 64];                                            \
        bb[SET][1] = bP1[sc_ * 64];                                            \
        bb[SET][2] = bP2[sc_ * 64]; } while (0)

#define LDA4(SET, G) do { const int gc_ = (G) < 16 ? (G) : 15;                 \
        awq[SET][0] = *(const us4*)(aR + 0 * 16 * (HID / 8) + gc_ * 16);       \
        awq[SET][1] = *(const us4*)(aR + 1 * 16 * (HID / 8) + gc_ * 16);       \
        awq[SET][2] = *(const us4*)(aR + 2 * 16 * (HID / 8) + gc_ * 16);       \
        awq[SET][3] = *(const us4*)(aR + 3 * 16 * (HID / 8) + gc_ * 16); } while (0)

#define EXPAND(AF, W) do { unsigned by_ = ((W) >> fk) & 0xFFu;                 \
        u32x2 lo_ = lut[by_ & 15u];                                            \
        u32x2 hi_ = lut[by_ >> 4];                                             \
        ((u32x2*)&(AF))[0] = lo_;                                              \
        ((u32x2*)&(AF))[1] = hi_; } while (0)

#define STEP(BSET, ASET, COMP) do {                                            \
        us8 a0_, a1_, a2_, a3_;                                                \
        EXPAND(a0_, awq[ASET][0][COMP]);                                       \
        EXPAND(a1_, awq[ASET][1][COMP]);                                       \
        EXPAND(a2_, awq[ASET][2][COMP]);                                       \
        EXPAND(a3_, awq[ASET][3][COMP]);                                       \
        bf16x8 b0_ = *(const bf16x8*)&bb[BSET][0];                             \
        bf16x8 b1_ = *(const bf16x8*)&bb[BSET][1];                             \
        bf16x8 b2_ = *(const bf16x8*)&bb[BSET][2];                             \
        bf16x8 fa0_ = *(const bf16x8*)&a0_;                                    \
        bf16x8 fa1_ = *(const bf16x8*)&a1_;                                    \
        bf16x8 fa2_ = *(const bf16x8*)&a2_;                                    \
        bf16x8 fa3_ = *(const bf16x8*)&a3_;                                    \
        acc[0] = __builtin_amdgcn_mfma_f32_16x16x32_bf16(fa0_, b0_, acc[0], 0, 0, 0); \
        acc[0] = __builtin_amdgcn_mfma_f32_16x16x32_bf16(fa0_, b1_, acc[0], 0, 0, 0); \
        acc[0] = __builtin_amdgcn_mfma_f32_16x16x32_bf16(fa0_, b2_, acc[0], 0, 0, 0); \
        acc[1] = __builtin_amdgcn_mfma_f32_16x16x32_bf16(fa1_, b0_, acc[1], 0, 0, 0); \
        acc[1] = __builtin_amdgcn_mfma_f32_16x16x32_bf16(fa1_, b1_, acc[1], 0, 0, 0); \
        acc[1] = __builtin_amdgcn_mfma_f32_16x16x32_bf16(fa1_, b2_, acc[1], 0, 0, 0); \
        acc[2] = __builtin_amdgcn_mfma_f32_16x16x32_bf16(fa2_, b0_, acc[2], 0, 0, 0); \
        acc[2] = __builtin_amdgcn_mfma_f32_16x16x32_bf16(fa2_, b1_, acc[2], 0, 0, 0); \
        acc[2] = __builtin_amdgcn_mfma_f32_16x16x32_bf16(fa2_, b2_, acc[2], 0, 0, 0); \
        acc[3] = __builtin_amdgcn_mfma_f32_16x16x32_bf16(fa3_, b0_, acc[3], 0, 0, 0); \
        acc[3] = __builtin_amdgcn_mfma_f32_16x16x32_bf16(fa3_, b1_, acc[3], 0, 0, 0); \
        acc[3] = __builtin_amdgcn_mfma_f32_16x16x32_bf16(fa3_, b2_, acc[3], 0, 0, 0); \
    } while (0)

    LDB4(0, 0); LDB4(1, 1);
    LDA4(0, 0); LDA4(1, 1);

    for (int g = 0; g < 16; g += 2) {
        const int s0 = g * 4;
        STEP(0, 0, 0); LDB4(0, s0 + 2);
        STEP(1, 0, 1); LDB4(1, s0 + 3);
        STEP(0, 0, 2); LDB4(0, s0 + 4);
        STEP(1, 0, 3); LDB4(1, s0 + 5);
        LDA4(0, g + 2);
        STEP(0, 1, 0); LDB4(0, s0 + 6);
        STEP(1, 1, 1); LDB4(1, s0 + 7);
        STEP(0, 1, 2); LDB4(0, s0 + 8);
        STEP(1, 1, 3); LDB4(1, s0 + 9);
        LDA4(1, g + 3);
    }

#undef LDB4
#undef LDA4
#undef EXPAND
#undef STEP

    lif_epi4c(acc, bias, memOut, sbitsOut, rowBase, bn * 32 + cg * 16, lane);
}

// ===========================================================================
// V4 Layer 1 (verified): LDS single-buffered As[3]+Bs[3] (30720 B)
// ===========================================================================
__device__ __forceinline__ void role_l1s(unsigned char* smem,
    const unsigned short* __restrict__ Ap,
    const unsigned short* __restrict__ Wp,
    const float* __restrict__ bias, float* __restrict__ memOut,
    unsigned char* __restrict__ sbitsOut, int rb, int tid)
{
    auto As = reinterpret_cast<unsigned short(*)[64 * 40]>(smem);              // [3]
    auto Bs = reinterpret_cast<unsigned short(*)[64 * 40]>(smem + 15360);      // [3]
    const size_t APS = (size_t)BSZ * DIN;
    const size_t BPS = (size_t)HID * DIN;

    const int bn = rb & 31, bm = rb >> 5;
    const int srow = tid >> 2, skq = tid & 3;
    const int lane = tid & 63, wv = tid >> 6;
    const int wm = wv >> 1, wn = wv & 1;
    const int fr = lane & 15, fk = (lane >> 4) * 8;
    const size_t aRow = (size_t)(bm * 64 + srow) * DIN;
    const size_t bRow = (size_t)(bn * 64 + srow) * DIN;
    const int sdst = srow * 40 + skq * 8;

    f32x4 acc[2][2] = {};
    us8 aa0, aa1, aa2, bb0, bb1, bb2;

    auto ldnext = [&](int k0) {
        aa0 = *(const us8*)(Ap + aRow + k0 + skq * 8);
        aa1 = *(const us8*)(Ap + APS + aRow + k0 + skq * 8);
        aa2 = *(const us8*)(Ap + 2 * APS + aRow + k0 + skq * 8);
        bb0 = *(const us8*)(Wp + bRow + k0 + skq * 8);
        bb1 = *(const us8*)(Wp + BPS + bRow + k0 + skq * 8);
        bb2 = *(const us8*)(Wp + 2 * BPS + bRow + k0 + skq * 8);
    };
    auto stageAB = [&]() {
        *(us8*)&As[0][sdst] = aa0;
        *(us8*)&As[1][sdst] = aa1;
        *(us8*)&As[2][sdst] = aa2;
        *(us8*)&Bs[0][sdst] = bb0;
        *(us8*)&Bs[1][sdst] = bb1;
        *(us8*)&Bs[2][sdst] = bb2;
    };

    ldnext(0); stageAB();
    __syncthreads();

    const int nsteps = DIN / 32;      // 32
    for (int s = 0; s < nsteps; s++) {
        const bool more = (s + 1 < nsteps);
        if (more) ldnext((s + 1) * 32);

        bf16x8 af[3][2], bf[3][2];
#pragma unroll
        for (int p = 0; p < 3; p++)
#pragma unroll
            for (int f = 0; f < 2; f++) {
                af[p][f] = *(const bf16x8*)&As[p][(wm * 32 + f * 16 + fr) * 40 + fk];
                bf[p][f] = *(const bf16x8*)&Bs[p][(wn * 32 + f * 16 + fr) * 40 + fk];
            }
#pragma unroll
        for (int pa = 0; pa < 3; pa++)
#pragma unroll
            for (int pb = 0; pb < 3; pb++) {
                if (pa + pb <= 2) {
#pragma unroll
                    for (int fm = 0; fm < 2; fm++)
#pragma unroll
                        for (int fn = 0; fn < 2; fn++)
                            acc[fm][fn] = __builtin_amdgcn_mfma_f32_16x16x32_bf16(
                                af[pa][fm], bf[pb][fn], acc[fm][fn], 0, 0, 0);
                }
            }

        __syncthreads();
        if (more) stageAB();
        __syncthreads();
    }

    lif_epi(acc, bias, memOut, sbitsOut, bm, bn, wm, wn, lane);
}

// ---------------------------------------------------------------------------
// V10 fused pipeline step (diagonal j), grid 1024 = 4 blocks/CU:
//   L1(t=j):256 | L2(t=j-1):256 | L3(t=j-2):256 | XS(t=j+1)+OUT(t=j-3):256
// ---------------------------------------------------------------------------
__global__ __launch_bounds__(256, 4)
void snn_step10(const float* __restrict__ x,
                unsigned short* __restrict__ xp,
                const unsigned short* __restrict__ w1p, const float* __restrict__ b1,
                const unsigned short* __restrict__ w2q, const float* __restrict__ b2,
                const unsigned short* __restrict__ w3q, const float* __restrict__ b3,
                const float* __restrict__ wo, const float* __restrict__ bo,
                float* __restrict__ mem1, float* __restrict__ mem2, float* __restrict__ mem3,
                float* __restrict__ memo,
                unsigned char* __restrict__ spk1, unsigned char* __restrict__ spk2,
                unsigned char* __restrict__ spk3,
                float* __restrict__ ssum, int j)
{
    __shared__ __align__(16) unsigned char smem[30720];
    const int bid = blockIdx.x, tid = threadIdx.x;
    const size_t XSLOT = (size_t)3 * BSZ * DIN;

    if (bid < 256) {
        const int t = j;
        if (t <= TSTEPS - 1)
            role_l1s(smem, xp + (size_t)(t & 1) * XSLOT, w1p, b1, mem1,
                     spk1 + (size_t)(t & 1) * SPKB, bid, tid);
    } else if (bid < 512) {
        const int t = j - 1;
        if (t >= 0 && t <= TSTEPS - 1)
            role_l23p(smem, spk1 + (size_t)(t & 1) * SPKB, w2q, b2, mem2,
                      spk2 + (size_t)(t & 1) * SPKB, bid - 256, tid);
    } else if (bid < 768) {
        const int t = j - 2;
        if (t >= 0 && t <= TSTEPS - 1)
            role_l23p(smem, spk2 + (size_t)(t & 1) * SPKB, w3q, b3, mem3,
                      spk3 + (size_t)(t & 1) * SPKB, bid - 512, tid);
    } else {
        const int t1 = j + 1;
        if (t1 <= TSTEPS - 1)
            xsplit_dev(x + (size_t)t1 * BSZ * DIN,
                       xp + (size_t)(t1 & 1) * XSLOT, bid - 768, 256, tid);
        const int t = j - 3;
        if (t >= 0 && t <= TSTEPS - 1) {
            const int lane = tid & 63, wvi = tid >> 6;
            if (wvi < 2)
                role_out_b(spk3 + (size_t)(t & 1) * SPKB, wo, bo, memo, ssum,
                           (bid - 768) * 2 + wvi, lane);
        }
    }
}

// ---------------------------------------------------------------------------
extern "C" void kernel_launch(void* const* d_in, const int* in_sizes, int n_in,
                              void* d_out, int out_size, void* d_ws, size_t ws_size,
                              hipStream_t stream)
{
    const float* x  = (const float*)d_in[0];
    const float* w1 = (const float*)d_in[1];
    const float* b1 = (const float*)d_in[2];
    const float* m1 = (const float*)d_in[3];
    const float* w2 = (const float*)d_in[4];
    const float* b2 = (const float*)d_in[5];
    const float* m2 = (const float*)d_in[6];
    const float* w3 = (const float*)d_in[7];
    const float* b3 = (const float*)d_in[8];
    const float* m3 = (const float*)d_in[9];
    const float* wo = (const float*)d_in[10];
    const float* bo = (const float*)d_in[11];
    float* out = (float*)d_out;

    const size_t planeB  = (size_t)HID * HID * 2;   // 8,388,608
    const size_t plane1B = (size_t)HID * DIN * 2;   // 4,194,304
    const size_t planeXB = (size_t)BSZ * DIN * 2;   // 1,048,576
    const size_t memB    = (size_t)BSZ * HID * 4;   // 4,194,304
    const size_t memoB   = (size_t)BSZ * NCLS * 4;  // 20,480
    const size_t spk2B   = 2 * SPKB;                // 262,144

    unsigned char* base = (unsigned char*)d_ws;
    const int nW1  = HID * DIN / 4;
    const size_t HD = (size_t)HID * DIN;

    const size_t needV10 = 6 * planeB + 3 * plane1B + 6 * planeXB
                         + 3 * memB + memoB + 3 * spk2B + 4096;   // 82,599,936
    if (ws_size < needV10) return;   // harness provides more (verified R4-R9)

    unsigned short* w2q = (unsigned short*)base;
    unsigned short* w3q = (unsigned short*)(base + 3 * planeB);
    unsigned short* w1p = (unsigned short*)(base + 6 * planeB);
    unsigned short* xp  = (unsigned short*)(base + 6 * planeB + 3 * plane1B);
    unsigned char* mbase = base + 6 * planeB + 3 * plane1B + 6 * planeXB;
    float* mem1 = (float*)(mbase);
    float* mem2 = (float*)(mbase + memB);
    float* mem3 = (float*)(mbase + 2 * memB);
    float* memo = (float*)(mbase + 3 * memB);
    unsigned char* spk1 = mbase + 3 * memB + memoB;
    unsigned char* spk2 = spk1 + spk2B;
    unsigned char* spk3 = spk2 + spk2B;

    split3q<<<2048, 256, 0, stream>>>(w2, m2, w2q);
    split3q<<<2048, 256, 0, stream>>>(w3, m3, w3q);
    split3<<<1024, 256, 0, stream>>>(w1, m1, w1p, w1p + HD, w1p + 2 * HD, nW1);
    xsplit_k<<<256, 256, 0, stream>>>(x, xp);   // t=0 into slot 0

    zerof<<<1024, 256, 0, stream>>>(mem1, (int)((3 * memB + memoB) / 16));
    zerof<<<8, 256, 0, stream>>>(out, (BSZ * NCLS) / 4);

    for (int j = 0; j <= TSTEPS + 2; j++) {   // 35 diagonals
        snn_step10<<<1024, 256, 0, stream>>>(x, xp, w1p, b1, w2q, b2, w3q, b3,
                                             wo, bo, mem1, mem2, mem3, memo,
                                             spk1, spk2, spk3, out, j);
    }
}